// Round 3
// baseline (809.253 us; speedup 1.0000x reference)
//
#include <hip/hip_runtime.h>

// Triaffine: s[b,z,x,y] = sum_{i,j,k} xb[b,x,i] * W[0,i,k,j] * pz[b,z,k] * yb[b,y,j]
// xb = [lrelu(x@Wx^T+bx), 1], yb = [lrelu(y@Wy^T+by), 1], pz = lrelu(y@Wz^T+bz)  (pz from y — faithful)
// Strategy: K1 projections (transposed stores) -> K2 w[bz][i][j] -> K3 per-(bz,yhalf): t = w@yb^T (LDS), s = xb@t.

#define LRELU(v) ((v) > 0.f ? (v) : 0.1f * (v))

constexpr int Bb   = 2;
constexpr int Ll   = 320;
constexpr int NIN  = 500;
constexpr int NP   = 100;
constexpr int NP1  = 101;
constexpr int NPAD = 104;          // j/i padded pitch in global arrays
constexpr int BL   = Bb * Ll;      // 640

// workspace layout (floats)
constexpr size_t SZ_XBT = (size_t)Bb * NPAD * Ll;          // [2][104][320]
constexpr size_t SZ_YBT = (size_t)Bb * NPAD * Ll;
constexpr size_t SZ_PZT = (size_t)NP * BL;                 // [100][640]
constexpr size_t SZ_W   = (size_t)BL * NP1 * NPAD;         // [640][101][104]
constexpr size_t OFF_XBT = 0;
constexpr size_t OFF_YBT = OFF_XBT + SZ_XBT;
constexpr size_t OFF_PZT = OFF_YBT + SZ_YBT;
constexpr size_t OFF_W   = OFF_PZT + SZ_PZT;
// total = 6,919,680 floats = 27.7 MB of d_ws

// ---------------- K1: projections ----------------
__global__ void k1_proj(const float* __restrict__ x, const float* __restrict__ y,
                        const float* __restrict__ Wx, const float* __restrict__ bx,
                        const float* __restrict__ Wy, const float* __restrict__ by,
                        const float* __restrict__ Wz, const float* __restrict__ bz,
                        float* __restrict__ xbT, float* __restrict__ ybT,
                        float* __restrict__ pzT) {
  __shared__ float sX[NIN], sY[NIN];
  int bl = blockIdx.x;
  int b = bl / Ll, l = bl % Ll;
  for (int c = threadIdx.x; c < NIN; c += blockDim.x) {
    sX[c] = x[(size_t)bl * NIN + c];
    sY[c] = y[(size_t)bl * NIN + c];
  }
  __syncthreads();
  for (int m = threadIdx.x; m < 3 * NP; m += blockDim.x) {
    int which = m / NP, o = m % NP;
    const float* Wr = (which == 0 ? Wx : (which == 1 ? Wy : Wz)) + (size_t)o * NIN;
    const float* s  = (which == 0 ? sX : sY);  // pz uses y (faithful to source)
    float acc = (which == 0 ? bx : (which == 1 ? by : bz))[o];
#pragma unroll 5
    for (int k4 = 0; k4 < NIN / 4; ++k4) {
      float4 wv = *(const float4*)&Wr[k4 * 4];
      acc = fmaf(wv.x, s[k4 * 4 + 0], acc);
      acc = fmaf(wv.y, s[k4 * 4 + 1], acc);
      acc = fmaf(wv.z, s[k4 * 4 + 2], acc);
      acc = fmaf(wv.w, s[k4 * 4 + 3], acc);
    }
    float v = LRELU(acc);
    if (which == 0)      xbT[((size_t)b * NPAD + o) * Ll + l] = v;
    else if (which == 1) ybT[((size_t)b * NPAD + o) * Ll + l] = v;
    else                 pzT[(size_t)o * BL + bl] = v;
  }
  if (threadIdx.x == 0) {  // ones rows (bias-augmented last column)
    xbT[((size_t)b * NPAD + NP) * Ll + l] = 1.f;
    ybT[((size_t)b * NPAD + NP) * Ll + l] = 1.f;
  }
}

// ---------------- K2: w[bz][i][j] = sum_k pz[bz][k] * W[i][k][j] ----------------
// grid (101, 10): block = (i, bz-chunk of 64). threads 256: tm=tid&15 (4 bz each), tj=tid>>4 (<13, 8 j each)
__global__ void k2_wmix(const float* __restrict__ pzT, const float* __restrict__ W,
                        float* __restrict__ w) {
  __shared__ float sWi[NP * NPAD];   // [100][104], pads zeroed -> w pads come out 0
  __shared__ float sPz[50 * 64];     // k-chunk of 50 x 64 bz
  int i = blockIdx.x;
  int bz0 = blockIdx.y * 64;
  for (int c = threadIdx.x; c < NP * NP1; c += 256)
    sWi[(c / NP1) * NPAD + (c % NP1)] = W[(size_t)i * NP * NP1 + c];
  for (int c = threadIdx.x; c < NP * 3; c += 256)
    sWi[(c / 3) * NPAD + NP1 + (c % 3)] = 0.f;

  int tm = threadIdx.x & 15, tj = threadIdx.x >> 4;
  float acc[4][8];
#pragma unroll
  for (int m = 0; m < 4; ++m)
#pragma unroll
    for (int q = 0; q < 8; ++q) acc[m][q] = 0.f;

  for (int kc = 0; kc < 2; ++kc) {
    int k0 = kc * 50;
    __syncthreads();
    for (int c = threadIdx.x; c < 50 * 16; c += 256) {
      int kk = c / 16, m4 = c % 16;
      *(float4*)&sPz[kk * 64 + m4 * 4] =
          *(const float4*)&pzT[(size_t)(k0 + kk) * BL + bz0 + m4 * 4];
    }
    __syncthreads();
    if (tj < 13) {
      for (int kk = 0; kk < 50; ++kk) {
        float4 av = *(const float4*)&sPz[kk * 64 + tm * 4];
        float4 b0 = *(const float4*)&sWi[(k0 + kk) * NPAD + tj * 8];
        float4 b1 = *(const float4*)&sWi[(k0 + kk) * NPAD + tj * 8 + 4];
        float aa[4] = {av.x, av.y, av.z, av.w};
        float bb[8] = {b0.x, b0.y, b0.z, b0.w, b1.x, b1.y, b1.z, b1.w};
#pragma unroll
        for (int m = 0; m < 4; ++m)
#pragma unroll
          for (int q = 0; q < 8; ++q) acc[m][q] = fmaf(aa[m], bb[q], acc[m][q]);
      }
    }
  }
  if (tj < 13) {
#pragma unroll
    for (int m = 0; m < 4; ++m) {
      size_t base = ((size_t)(bz0 + tm * 4 + m) * NP1 + i) * NPAD + tj * 8;
      *(float4*)&w[base]     = make_float4(acc[m][0], acc[m][1], acc[m][2], acc[m][3]);
      *(float4*)&w[base + 4] = make_float4(acc[m][4], acc[m][5], acc[m][6], acc[m][7]);
    }
  }
}

// ---------------- K3: per (bz, y-half): t = w @ yb^T (LDS), s = xb @ t ----------------
// grid 1280 = (bz 640) x (yh 2). 256 threads: ty=tid&15, th=tid>>4.
// phase A: t[i][y] = sum_j wT[j][i] * ybT[j][y]   (i-tile 8 per th<13, y: 32g+2ty+p, 10 per ty)
// phase B: s[x][y] = sum_i xbT[i][x] * t[i][y]    (x = xg*160 + th*10 + xx, a from L2 broadcast)
__launch_bounds__(256, 1)
__global__ void k3_score(const float* __restrict__ w, const float* __restrict__ xbT,
                         const float* __restrict__ ybT, float* __restrict__ out) {
  __shared__ float sWT[NPAD * 108];  // [104 j][108 i]  (rows 101-103 staged but never read)
  __shared__ float sYB[26 * 160];    // j-chunk of yb^T half-rows
  __shared__ float sT[NP1 * 160];    // t[i][y]
  // total LDS = (11232 + 4160 + 16160) * 4 = 126,208 B  (<128 KiB, 1 block/CU)

  int bid = blockIdx.x;
  int bz = bid >> 1, yh = bid & 1;
  int b = bz / Ll;
  int tid = threadIdx.x;
  int ty = tid & 15, th = tid >> 4;

  // stage w[bz] transposed into sWT[j][i]
  const float* wsrc = w + (size_t)bz * NP1 * NPAD;
  for (int c4 = tid; c4 < (NP1 * NPAD) / 4; c4 += 256) {
    int c = c4 * 4;
    int i = c / NPAD, j = c % NPAD;   // NPAD multiple of 4: all 4 elems same i
    float4 v = *(const float4*)&wsrc[c];
    sWT[(j + 0) * 108 + i] = v.x;
    sWT[(j + 1) * 108 + i] = v.y;
    sWT[(j + 2) * 108 + i] = v.z;
    sWT[(j + 3) * 108 + i] = v.w;
  }

  const float* ybsrc = ybT + (size_t)b * NPAD * Ll + yh * 160;
  float accA[8][10];
#pragma unroll
  for (int ii = 0; ii < 8; ++ii)
#pragma unroll
    for (int q = 0; q < 10; ++q) accA[ii][q] = 0.f;

  // phase A over j in 4 chunks of <=26
  for (int ch = 0; ch < 4; ++ch) {
    int j0 = ch * 26;
    int len = (ch == 3) ? (NP1 - 78) : 26;   // 26,26,26,23
    __syncthreads();
    for (int c = tid; c < len * 40; c += 256) {
      int jj = c / 40, y4 = c % 40;
      *(float4*)&sYB[jj * 160 + y4 * 4] =
          *(const float4*)&ybsrc[(size_t)(j0 + jj) * Ll + y4 * 4];
    }
    __syncthreads();
    if (th < 13) {
      for (int jj = 0; jj < len; ++jj) {
        int jr = j0 + jj;
        float4 a0 = *(const float4*)&sWT[jr * 108 + th * 8];
        float4 a1 = *(const float4*)&sWT[jr * 108 + th * 8 + 4];
        float aa[8] = {a0.x, a0.y, a0.z, a0.w, a1.x, a1.y, a1.z, a1.w};
        float bv[10];
#pragma unroll
        for (int g = 0; g < 5; ++g) {
          float2 t2 = *(const float2*)&sYB[jj * 160 + 32 * g + 2 * ty];
          bv[2 * g] = t2.x;
          bv[2 * g + 1] = t2.y;
        }
#pragma unroll
        for (int ii = 0; ii < 8; ++ii)
#pragma unroll
          for (int q = 0; q < 10; ++q)
            accA[ii][q] = fmaf(aa[ii], bv[q], accA[ii][q]);
      }
    }
  }

  // write t (only i < 101)
#pragma unroll
  for (int ii = 0; ii < 8; ++ii) {
    int i = th * 8 + ii;
    if (i < NP1) {
#pragma unroll
      for (int g = 0; g < 5; ++g)
        *(float2*)&sT[i * 160 + 32 * g + 2 * ty] =
            make_float2(accA[ii][2 * g], accA[ii][2 * g + 1]);
    }
  }
  __syncthreads();

  // phase B
  const float* xbsrc = xbT + (size_t)b * NPAD * Ll;
  float* obase = out + (size_t)bz * Ll * Ll + (size_t)yh * 160;
  for (int xg = 0; xg < 2; ++xg) {
    float acc[10][10];
#pragma unroll
    for (int xx = 0; xx < 10; ++xx)
#pragma unroll
      for (int q = 0; q < 10; ++q) acc[xx][q] = 0.f;
    int x0 = xg * 160 + th * 10;
#pragma unroll 2
    for (int i = 0; i < NP1; ++i) {
      float aa[10];
#pragma unroll
      for (int u = 0; u < 5; ++u) {
        float2 a2 = *(const float2*)&xbsrc[(size_t)i * Ll + x0 + 2 * u];
        aa[2 * u] = a2.x;
        aa[2 * u + 1] = a2.y;
      }
      float bv[10];
#pragma unroll
      for (int g = 0; g < 5; ++g) {
        float2 t2 = *(const float2*)&sT[i * 160 + 32 * g + 2 * ty];
        bv[2 * g] = t2.x;
        bv[2 * g + 1] = t2.y;
      }
#pragma unroll
      for (int xx = 0; xx < 10; ++xx)
#pragma unroll
        for (int q = 0; q < 10; ++q)
          acc[xx][q] = fmaf(aa[xx], bv[q], acc[xx][q]);
    }
#pragma unroll
    for (int xx = 0; xx < 10; ++xx) {
      float* orow = obase + (size_t)(x0 + xx) * Ll;
#pragma unroll
      for (int g = 0; g < 5; ++g)
        *(float2*)&orow[32 * g + 2 * ty] =
            make_float2(acc[xx][2 * g], acc[xx][2 * g + 1]);
    }
  }
}

extern "C" void kernel_launch(void* const* d_in, const int* in_sizes, int n_in,
                              void* d_out, int out_size, void* d_ws, size_t ws_size,
                              hipStream_t stream) {
  (void)in_sizes; (void)n_in; (void)out_size; (void)ws_size;
  const float* x  = (const float*)d_in[0];
  const float* y  = (const float*)d_in[1];
  // d_in[2] = z : unused (reference applies mlp_z to y)
  const float* Wx = (const float*)d_in[3];
  const float* bx = (const float*)d_in[4];
  const float* Wy = (const float*)d_in[5];
  const float* by = (const float*)d_in[6];
  const float* Wz = (const float*)d_in[7];
  const float* bz = (const float*)d_in[8];
  const float* W  = (const float*)d_in[9];
  float* out = (float*)d_out;

  float* ws  = (float*)d_ws;          // needs 27,678,720 B of d_ws
  float* xbT = ws + OFF_XBT;
  float* ybT = ws + OFF_YBT;
  float* pzT = ws + OFF_PZT;
  float* wbuf = ws + OFF_W;

  k1_proj<<<BL, 256, 0, stream>>>(x, y, Wx, bx, Wy, by, Wz, bz, xbT, ybT, pzT);
  k2_wmix<<<dim3(NP1, 10), 256, 0, stream>>>(pzT, W, wbuf);
  k3_score<<<BL * 2, 256, 0, stream>>>(wbuf, xbT, ybT, out);
}

// Round 5
// 623.706 us; speedup vs baseline: 1.2975x; 1.2975x over previous
//
#include <hip/hip_runtime.h>
#include <hip/hip_fp16.h>

// Triaffine: s[b,z,x,y] = sum_{i,j,k} xb[b,x,i] * W[0,i,k,j] * pz[b,z,k] * yb[b,y,j]
// xb=[lrelu(x@Wx^T+bx),1], yb=[lrelu(y@Wy^T+by),1], pz=lrelu(y@Wz^T+bz)  (pz from y — faithful)
// R5: K0 WT transpose -> K1 coalesced proj -> K2 w[bz][i][j]
//     -> k3_fused per (bz,yh): phase A t=w@yb^T into 33.3KB fp16 LDS (no global t), phase B s=xb@t.
// ws footprint 28.3MB (proven-safe scale; R4's 70.9MB global-t suspected OOB -> container death).

#define LRELU(v) ((v) > 0.f ? (v) : 0.1f * (v))

constexpr int Bb   = 2;
constexpr int Ll   = 320;
constexpr int NIN  = 500;
constexpr int NP   = 100;
constexpr int NP1  = 101;
constexpr int NPAD = 104;            // padded i/j pitch
constexpr int BL   = Bb * Ll;        // 640
constexpr int MTOT = 3 * NP;         // 300 fused projection rows
constexpr int MPITCH = 304;          // WT column pitch

// workspace layout (float units)
constexpr size_t SZ_XBT = (size_t)Bb * NPAD * Ll;       // 66,560
constexpr size_t SZ_YBT = (size_t)Bb * NPAD * Ll;       // 66,560
constexpr size_t SZ_PZT = (size_t)NP * BL;              // 64,000
constexpr size_t SZ_WT  = (size_t)NIN * MPITCH;         // 152,000
constexpr size_t SZ_W   = (size_t)BL * NP1 * NPAD;      // 6,722,560
constexpr size_t OFF_XBT = 0;
constexpr size_t OFF_YBT = OFF_XBT + SZ_XBT;
constexpr size_t OFF_PZT = OFF_YBT + SZ_YBT;
constexpr size_t OFF_WT  = OFF_PZT + SZ_PZT;
constexpr size_t OFF_W   = OFF_WT + SZ_WT;
// total = 7,071,680 floats = 28,286,720 B of d_ws

// ---------------- K0: transpose [Wx;Wy;Wz] (300x500) -> WT[k][m] (500x304) ----------------
__global__ void k0_wt(const float* __restrict__ Wx, const float* __restrict__ Wy,
                      const float* __restrict__ Wz, float* __restrict__ WT) {
  __shared__ float tile[32][33];
  int k0 = blockIdx.x * 32, m0 = blockIdx.y * 32;
  int tx = threadIdx.x & 31, tz = threadIdx.x >> 5;   // tz 0..7
#pragma unroll
  for (int rr = 0; rr < 4; ++rr) {
    int m = m0 + tz * 4 + rr;
    int k = k0 + tx;
    float v = 0.f;
    if (m < MTOT && k < NIN) {
      const float* src = m < NP ? Wx : (m < 2 * NP ? Wy : Wz);
      int o = m - (m < NP ? 0 : (m < 2 * NP ? NP : 2 * NP));
      v = src[(size_t)o * NIN + k];
    }
    tile[tz * 4 + rr][tx] = v;
  }
  __syncthreads();
#pragma unroll
  for (int rr = 0; rr < 4; ++rr) {
    int k = k0 + tz * 4 + rr;
    int m = m0 + tx;
    if (k < NIN && m < MTOT) WT[(size_t)k * MPITCH + m] = tile[tx][tz * 4 + rr];
  }
}

// ---------------- K1: projections (coalesced weight reads via WT) ----------------
__global__ void k1_proj(const float* __restrict__ x, const float* __restrict__ y,
                        const float* __restrict__ WT,
                        const float* __restrict__ bx, const float* __restrict__ by,
                        const float* __restrict__ bzv,
                        float* __restrict__ xbT, float* __restrict__ ybT,
                        float* __restrict__ pzT) {
  __shared__ float sX[NIN], sY[NIN];
  int bl = blockIdx.x;
  int b = bl / Ll, l = bl % Ll;
  int tid = threadIdx.x;
  {
    const float4* x4 = (const float4*)(x + (size_t)bl * NIN);
    const float4* y4 = (const float4*)(y + (size_t)bl * NIN);
    if (tid < NIN / 4) {                       // 125 float4 each
      ((float4*)sX)[tid] = x4[tid];
      ((float4*)sY)[tid] = y4[tid];
    }
  }
  __syncthreads();
  for (int m = tid; m < MTOT; m += 256) {
    int which = m / NP, o = m - which * NP;
    const float* s = which == 0 ? sX : sY;     // pz uses y (faithful)
    float acc = (which == 0 ? bx : (which == 1 ? by : bzv))[o];
#pragma unroll 4
    for (int k = 0; k < NIN; ++k)
      acc = fmaf(WT[(size_t)k * MPITCH + m], s[k], acc);  // consecutive m -> coalesced
    float v = LRELU(acc);
    if (which == 0)      xbT[((size_t)b * NPAD + o) * Ll + l] = v;
    else if (which == 1) ybT[((size_t)b * NPAD + o) * Ll + l] = v;
    else                 pzT[(size_t)o * BL + bl] = v;
  }
  if (tid == 0) {   // bias-augmentation rows
    xbT[((size_t)b * NPAD + NP) * Ll + l] = 1.f;
    ybT[((size_t)b * NPAD + NP) * Ll + l] = 1.f;
  }
  if (tid < 3)      // zero xbT pad rows 101..103 (phase B reads i<104 uniformly)
    xbT[((size_t)b * NPAD + NP1 + tid) * Ll + l] = 0.f;
}

// ---------------- K2: w[bz][i][j] = sum_k pz[bz][k] * W[i][k][j] ----------------
__global__ void k2_wmix(const float* __restrict__ pzT, const float* __restrict__ W,
                        float* __restrict__ w) {
  __shared__ float sWi[NP * NPAD];   // [100][104], pad cols zeroed -> w pad cols 0
  __shared__ float sPz[50 * 64];
  int i = blockIdx.x;
  int bz0 = blockIdx.y * 64;
  for (int c = threadIdx.x; c < NP * NP1; c += 256)
    sWi[(c / NP1) * NPAD + (c % NP1)] = W[(size_t)i * NP * NP1 + c];
  for (int c = threadIdx.x; c < NP * 3; c += 256)
    sWi[(c / 3) * NPAD + NP1 + (c % 3)] = 0.f;

  int tm = threadIdx.x & 15, tj = threadIdx.x >> 4;
  float acc[4][8];
#pragma unroll
  for (int m = 0; m < 4; ++m)
#pragma unroll
    for (int q = 0; q < 8; ++q) acc[m][q] = 0.f;

  for (int kc = 0; kc < 2; ++kc) {
    int k0 = kc * 50;
    __syncthreads();
    for (int c = threadIdx.x; c < 50 * 16; c += 256) {
      int kk = c / 16, m4 = c % 16;
      *(float4*)&sPz[kk * 64 + m4 * 4] =
          *(const float4*)&pzT[(size_t)(k0 + kk) * BL + bz0 + m4 * 4];
    }
    __syncthreads();
    if (tj < 13) {
      for (int kk = 0; kk < 50; ++kk) {
        float4 av = *(const float4*)&sPz[kk * 64 + tm * 4];
        float4 b0 = *(const float4*)&sWi[(k0 + kk) * NPAD + tj * 8];
        float4 b1 = *(const float4*)&sWi[(k0 + kk) * NPAD + tj * 8 + 4];
        float aa[4] = {av.x, av.y, av.z, av.w};
        float bb[8] = {b0.x, b0.y, b0.z, b0.w, b1.x, b1.y, b1.z, b1.w};
#pragma unroll
        for (int m = 0; m < 4; ++m)
#pragma unroll
          for (int q = 0; q < 8; ++q) acc[m][q] = fmaf(aa[m], bb[q], acc[m][q]);
      }
    }
  }
  if (tj < 13) {
#pragma unroll
    for (int m = 0; m < 4; ++m) {
      size_t base = ((size_t)(bz0 + tm * 4 + m) * NP1 + i) * NPAD + tj * 8;
      *(float4*)&w[base]     = make_float4(acc[m][0], acc[m][1], acc[m][2], acc[m][3]);
      *(float4*)&w[base + 4] = make_float4(acc[m][4], acc[m][5], acc[m][6], acc[m][7]);
    }
  }
}

// ---------------- k3_fused: per (bz, yh) ----------------
// phase A: t[i][y] = sum_j w[bz][i][j]*ybT[b][j][y] -> fp16 LDS [104][160] (33.3KB)
//   th<13: 8 i-rows each (clamped at 100, masked-zero at store); y = yh*160 + 32u + 2ty (coalesced).
// phase B: s[x][y] = sum_i xbT[b][i][x] * sT[i][y]; xg in {0,1}: x0 = xg*160 + th*10.
__global__ __launch_bounds__(256) void k3_fused(const float* __restrict__ w,
                                                const float* __restrict__ xbT,
                                                const float* __restrict__ ybT,
                                                float* __restrict__ out) {
  __shared__ __half sT[NPAD * 160];   // 33,280 B -> ~3-4 blocks/CU
  int bid = blockIdx.x;
  int bz = bid >> 1, yh = bid & 1;
  int b = bz / Ll;
  int tid = threadIdx.x, ty = tid & 15, th = tid >> 4;

  if (th < 13) {
    const float* yb = ybT + (size_t)b * NPAD * Ll + yh * 160 + 2 * ty;
    const float* wb = w + (size_t)bz * (NP1 * NPAD);
    const float* wrow[8];
#pragma unroll
    for (int ii = 0; ii < 8; ++ii) {
      int i = th * 8 + ii;
      if (i > NP) i = NP;              // clamp rows 101..103 (no OOB; zeroed at store)
      wrow[ii] = wb + (size_t)i * NPAD;
    }
    float acc[8][10];
#pragma unroll
    for (int ii = 0; ii < 8; ++ii)
#pragma unroll
      for (int q = 0; q < 10; ++q) acc[ii][q] = 0.f;

#pragma unroll 2
    for (int j = 0; j < NPAD; ++j) {   // w pad cols are 0 -> yb pad rows contribute 0
      float bv[10];
#pragma unroll
      for (int u = 0; u < 5; ++u) {
        float2 t2 = *(const float2*)&yb[(size_t)j * Ll + 32 * u];
        bv[2 * u] = t2.x; bv[2 * u + 1] = t2.y;
      }
      float aa[8];
#pragma unroll
      for (int ii = 0; ii < 8; ++ii) aa[ii] = wrow[ii][j];   // th-group broadcast
#pragma unroll
      for (int ii = 0; ii < 8; ++ii)
#pragma unroll
        for (int q = 0; q < 10; ++q) acc[ii][q] = fmaf(aa[ii], bv[q], acc[ii][q]);
    }
#pragma unroll
    for (int ii = 0; ii < 8; ++ii) {
      int i = th * 8 + ii;
      bool ok = (i < NP1);
#pragma unroll
      for (int u = 0; u < 5; ++u) {
        __half2 h;
        h.x = __float2half_rn(ok ? acc[ii][2 * u] : 0.f);
        h.y = __float2half_rn(ok ? acc[ii][2 * u + 1] : 0.f);
        *(__half2*)&sT[i * 160 + 32 * u + 2 * ty] = h;       // conflict-free (4B lane stride)
      }
    }
  }
  __syncthreads();

  const float* xb = xbT + (size_t)b * NPAD * Ll;
  float* obase = out + (size_t)bz * Ll * Ll + (size_t)yh * 160 + 2 * ty;
  for (int xg = 0; xg < 2; ++xg) {
    int x0 = xg * 160 + th * 10;
    float acc[10][10];
#pragma unroll
    for (int xx = 0; xx < 10; ++xx)
#pragma unroll
      for (int q = 0; q < 10; ++q) acc[xx][q] = 0.f;
#pragma unroll 2
    for (int i = 0; i < NPAD; ++i) {   // sT rows 101..103 zero; xbT pad rows zero
      float aa[10];
#pragma unroll
      for (int u = 0; u < 5; ++u) {
        float2 a2 = *(const float2*)&xb[(size_t)i * Ll + x0 + 2 * u];  // th-group broadcast
        aa[2 * u] = a2.x; aa[2 * u + 1] = a2.y;
      }
      float bv[10];
#pragma unroll
      for (int u = 0; u < 5; ++u) {
        __half2 hv = *(const __half2*)&sT[i * 160 + 32 * u + 2 * ty];  // conflict-free
        bv[2 * u] = __half2float(hv.x); bv[2 * u + 1] = __half2float(hv.y);
      }
#pragma unroll
      for (int xx = 0; xx < 10; ++xx)
#pragma unroll
        for (int q = 0; q < 10; ++q) acc[xx][q] = fmaf(aa[xx], bv[q], acc[xx][q]);
    }
#pragma unroll
    for (int xx = 0; xx < 10; ++xx) {
      float* orow = obase + (size_t)(x0 + xx) * Ll;
#pragma unroll
      for (int u = 0; u < 5; ++u)      // lanes consecutive 8B -> coalesced 128B/16-lane
        *(float2*)&orow[32 * u] = make_float2(acc[xx][2 * u], acc[xx][2 * u + 1]);
    }
  }
}

extern "C" void kernel_launch(void* const* d_in, const int* in_sizes, int n_in,
                              void* d_out, int out_size, void* d_ws, size_t ws_size,
                              hipStream_t stream) {
  (void)in_sizes; (void)n_in; (void)out_size; (void)ws_size;
  const float* x  = (const float*)d_in[0];
  const float* y  = (const float*)d_in[1];
  // d_in[2] = z : unused (reference applies mlp_z to y)
  const float* Wx = (const float*)d_in[3];
  const float* bx = (const float*)d_in[4];
  const float* Wy = (const float*)d_in[5];
  const float* by = (const float*)d_in[6];
  const float* Wz = (const float*)d_in[7];
  const float* bzv= (const float*)d_in[8];
  const float* W  = (const float*)d_in[9];
  float* out = (float*)d_out;

  float* ws   = (float*)d_ws;         // needs 28,286,720 B of d_ws
  float* xbT  = ws + OFF_XBT;
  float* ybT  = ws + OFF_YBT;
  float* pzT  = ws + OFF_PZT;
  float* WT   = ws + OFF_WT;
  float* wbuf = ws + OFF_W;

  k0_wt   <<<dim3(16, 10), 256, 0, stream>>>(Wx, Wy, Wz, WT);
  k1_proj <<<BL, 256, 0, stream>>>(x, y, WT, bx, by, bzv, xbT, ybT, pzT);
  k2_wmix <<<dim3(NP1, 10), 256, 0, stream>>>(pzT, W, wbuf);
  k3_fused<<<BL * 2, 256, 0, stream>>>(wbuf, xbT, ybT, out);
}